// Round 1
// baseline (188.751 us; speedup 1.0000x reference)
//
#include <hip/hip_runtime.h>
#include <hip/hip_bf16.h>
#include <math.h>

// Problem shape (fixed by setup_inputs): B=128, S=20, C=32000
#define NB 128
#define NS 20
#define NC 32000

// ---------------------------------------------------------------------------
// Kernel 1: restricted-softmax cost matrix.
// cost[b,i,j] = -log_softmax(outputs[b,i,gold[b,:]], over j)[j] * weight[gold[b,j]]
// One thread per (b,i) row; 20 gathers, softmax over 20, write 20 floats.
// ---------------------------------------------------------------------------
__global__ void cost_kernel(const float* __restrict__ outputs,
                            const int* __restrict__ gold,
                            const float* __restrict__ weight,
                            float* __restrict__ cost) {
    int r = blockIdx.x * blockDim.x + threadIdx.x;   // row over B*S
    if (r >= NB * NS) return;
    int b = r / NS;
    const int* g = gold + b * NS;
    const float* row = outputs + (size_t)r * NC;

    float x[NS];
    float mx = -INFINITY;
#pragma unroll
    for (int j = 0; j < NS; ++j) {
        x[j] = row[g[j]];
        mx = fmaxf(mx, x[j]);
    }
    float s = 0.f;
#pragma unroll
    for (int j = 0; j < NS; ++j) s += __expf(x[j] - mx);
    float lz = mx + __logf(s);

    float* crow = cost + (size_t)r * NS;
#pragma unroll
    for (int j = 0; j < NS; ++j) {
        float c = -(x[j] - lz) * weight[g[j]];
        if (isinf(c)) c = 1e8f;   // BIG, as reference
        crow[j] = c;
    }
}

// ---------------------------------------------------------------------------
// Kernel 2: Hungarian (shortest augmenting path with potentials), one wave
// (64 lanes) per batch. Lane j owns column j (j=0..20, 1-based cols).
// Exactly mirrors the reference's e-maxx algorithm in f64 on the f32 costs;
// argmin tie-breaks to the lowest index like np.argmin.
// match[b][row] = gold[b][assigned_col(row)]
// ---------------------------------------------------------------------------
__global__ __launch_bounds__(64) void hungarian_kernel(
        const float* __restrict__ cost,
        const int* __restrict__ gold,
        int* __restrict__ match) {
    const int b = blockIdx.x;
    const int lane = threadIdx.x;          // 0..63
    const int n = NS, m = NS;
    const float* cb = cost + (size_t)b * NS * NS;
    const double INF = (double)INFINITY;

    double u_r = 0.0;    // u[lane]   (rows, lanes 0..n)
    double v_j = 0.0;    // v[lane]   (cols, lanes 0..m)
    double minv_j = INF;
    int p_j = 0;         // p[lane]: row matched to col lane (0 = free)
    int way_j = 0;
    bool used_j = false;
    const bool is_col = (lane >= 1 && lane <= m);

    for (int i = 1; i <= n; ++i) {
        if (lane == 0) p_j = i;            // p[0] = i
        int j0 = 0;
        minv_j = INF;
        used_j = false;
        while (true) {
            if (lane == j0) used_j = true;
            int i0 = __shfl(p_j, j0);
            double u_i0 = __shfl(u_r, i0);
            if (is_col && !used_j) {
                double cur = (double)cb[(i0 - 1) * m + (lane - 1)] - u_i0 - v_j;
                if (cur < minv_j) { minv_j = cur; way_j = j0; }
            }
            double cand = (is_col && !used_j) ? minv_j : INF;
            int idx = lane;
            // full-wave butterfly min-reduce, low-index tie-break (np.argmin)
            for (int off = 1; off < 64; off <<= 1) {
                double ov = __shfl_xor(cand, off);
                int    oi = __shfl_xor(idx, off);
                if (ov < cand || (ov == cand && oi < idx)) { cand = ov; idx = oi; }
            }
            double delta = cand;
            int j1 = idx;
            // u[p[used]] += delta  (distinct rows; build a row bitmask)
            unsigned rm = (used_j && lane <= m) ? (1u << p_j) : 0u;
            for (int off = 1; off < 64; off <<= 1) rm |= __shfl_xor(rm, off);
            if (lane <= n && ((rm >> lane) & 1u)) u_r += delta;
            if (used_j)      v_j -= delta;       // v[used] -= delta (incl. j=0)
            else if (is_col) minv_j -= delta;    // minv[~used] -= delta
            j0 = j1;
            int pj0 = __shfl(p_j, j0);
            if (pj0 == 0) break;                 // reached a free column
        }
        // augment along way[] chain
        while (j0 != 0) {
            int j1  = __shfl(way_j, j0);
            int pj1 = __shfl(p_j, j1);
            if (lane == j0) p_j = pj1;           // p[j0] = p[j1]
            j0 = j1;
        }
    }
    // ans[p[j]-1] = j-1  ->  match[b][p[j]-1] = gold[b][j-1]
    if (is_col && p_j != 0) {
        match[b * NS + (p_j - 1)] = gold[b * NS + (lane - 1)];
    }
}

// ---------------------------------------------------------------------------
// Kernel 3: per-row logZ = max + log(sum exp(x - max)) over C=32000.
// One block (256 threads) per (b,s) row, float4 coalesced loads, online
// max/sum, shfl + LDS block reduce. Memory-bound: 327 MB total.
// ---------------------------------------------------------------------------
__global__ __launch_bounds__(256) void lse_kernel(
        const float* __restrict__ outputs,
        float* __restrict__ logZ) {
    const int row = blockIdx.x;
    const float4* rp = (const float4*)(outputs + (size_t)row * NC);
    const int n4 = NC / 4;   // 8000

    float m = -INFINITY;
    float s = 0.f;
    for (int idx = threadIdx.x; idx < n4; idx += blockDim.x) {
        float4 x = rp[idx];
        float m4 = fmaxf(fmaxf(x.x, x.y), fmaxf(x.z, x.w));
        float nm = fmaxf(m, m4);
        s = s * __expf(m - nm)
          + __expf(x.x - nm) + __expf(x.y - nm)
          + __expf(x.z - nm) + __expf(x.w - nm);
        m = nm;
    }
    // wave reduce (64 lanes)
    for (int off = 1; off < 64; off <<= 1) {
        float om = __shfl_xor(m, off);
        float os = __shfl_xor(s, off);
        float nm = fmaxf(m, om);
        s = s * __expf(m - nm) + os * __expf(om - nm);
        m = nm;
    }
    __shared__ float smx[4], ssm[4];
    int wid = threadIdx.x >> 6;
    if ((threadIdx.x & 63) == 0) { smx[wid] = m; ssm[wid] = s; }
    __syncthreads();
    if (threadIdx.x == 0) {
        float M = smx[0], S = ssm[0];
        for (int w = 1; w < (int)(blockDim.x >> 6); ++w) {
            float om = smx[w], os = ssm[w];
            float nm = fmaxf(M, om);
            S = S * __expf(M - nm) + os * __expf(om - nm);
            M = nm;
        }
        logZ[row] = M + __logf(S);
    }
}

// ---------------------------------------------------------------------------
// Kernel 4: final masked-mean NLL reduce. Deterministic tree reduce,
// double accumulation, single block.
// ---------------------------------------------------------------------------
__global__ __launch_bounds__(256) void final_kernel(
        const float* __restrict__ outputs,
        const int* __restrict__ match,
        const float* __restrict__ logZ,
        const float* __restrict__ weight,
        const unsigned char* __restrict__ mask,
        float* __restrict__ out) {
    double nsum = 0.0, msum = 0.0;
    for (int r = threadIdx.x; r < NB * NS; r += blockDim.x) {
        int mt = match[r];
        float x = outputs[(size_t)r * NC + mt];
        float nll = -(x - logZ[r]) * weight[mt];
        float mk = mask[r] ? 1.f : 0.f;
        nsum += (double)(nll * mk);
        msum += (double)mk;
    }
    for (int off = 1; off < 64; off <<= 1) {
        nsum += __shfl_xor(nsum, off);
        msum += __shfl_xor(msum, off);
    }
    __shared__ double sn[4], sm[4];
    int wid = threadIdx.x >> 6;
    if ((threadIdx.x & 63) == 0) { sn[wid] = nsum; sm[wid] = msum; }
    __syncthreads();
    if (threadIdx.x == 0) {
        double N = 0.0, M = 0.0;
        for (int w = 0; w < (int)(blockDim.x >> 6); ++w) { N += sn[w]; M += sm[w]; }
        out[0] = (float)(N / (M + 1e-8));
    }
}

// ---------------------------------------------------------------------------
extern "C" void kernel_launch(void* const* d_in, const int* in_sizes, int n_in,
                              void* d_out, int out_size, void* d_ws, size_t ws_size,
                              hipStream_t stream) {
    const float* outputs        = (const float*)d_in[0];          // [B,S,C] f32
    const int*   gold           = (const int*)d_in[1];            // [B,S] i32
    const unsigned char* mask   = (const unsigned char*)d_in[2];  // [B,S] bool
    const float* weight         = (const float*)d_in[3];          // [C] f32
    float* out = (float*)d_out;

    // workspace layout
    char* ws = (char*)d_ws;
    float* cost  = (float*)ws;                                  // B*S*S f32
    int*   match = (int*)(ws + (size_t)NB * NS * NS * 4);       // B*S i32
    float* logZ  = (float*)(ws + (size_t)NB * NS * NS * 4 + (size_t)NB * NS * 4);

    cost_kernel<<<(NB * NS + 255) / 256, 256, 0, stream>>>(outputs, gold, weight, cost);
    hungarian_kernel<<<NB, 64, 0, stream>>>(cost, gold, match);
    lse_kernel<<<NB * NS, 256, 0, stream>>>(outputs, logZ);
    final_kernel<<<1, 256, 0, stream>>>(outputs, match, logZ, weight, mask, out);
}

// Round 2
// 103.798 us; speedup vs baseline: 1.8185x; 1.8185x over previous
//
#include <hip/hip_runtime.h>
#include <hip/hip_bf16.h>
#include <math.h>

// Problem shape (fixed by setup_inputs): B=128, S=20, C=32000
#define NB 128
#define NS 20
#define NC 32000

// ---------------------------------------------------------------------------
// Mega kernel: heterogeneous blocks.
//   blockIdx.x <  NB          : fused cost + Hungarian for batch b (wave 0)
//   blockIdx.x >= NB          : per-row logsumexpZ over C=32000 (row = blockIdx-NB)
// The 128 Hungarian blocks are latency-bound; the 2560 LSE blocks are
// HBM-bound. Running them in one dispatch overlaps the two regimes.
// ---------------------------------------------------------------------------
__global__ __launch_bounds__(256) void mega_kernel(
        const float* __restrict__ outputs,
        const int* __restrict__ gold,
        const float* __restrict__ weight,
        int* __restrict__ match,
        float* __restrict__ logZ) {

    if (blockIdx.x < NB) {
        // =================== fused cost + Hungarian ===================
        const int b = blockIdx.x;
        const int* g = gold + b * NS;
        __shared__ float cst[NS * NS];   // sub logits, then cost, in place
        __shared__ float lzs[NS];        // per-row restricted logsumexp

        // phase 1: gather outputs[b, i, gold[b, j]]  (400 scattered loads)
        for (int e = threadIdx.x; e < NS * NS; e += blockDim.x) {
            int i = e / NS, j = e - i * NS;
            cst[e] = outputs[(size_t)(b * NS + i) * NC + g[j]];
        }
        __syncthreads();
        // phase 2: per-row logsumexp over the 20 gold columns
        if (threadIdx.x < NS) {
            int i = threadIdx.x;
            float mx = -INFINITY;
            for (int j = 0; j < NS; ++j) mx = fmaxf(mx, cst[i * NS + j]);
            float s = 0.f;
            for (int j = 0; j < NS; ++j) s += __expf(cst[i * NS + j] - mx);
            lzs[i] = mx + __logf(s);
        }
        __syncthreads();
        // phase 3: cost = -(x - lz) * w[gold[j]]   (BIG replaces inf)
        for (int e = threadIdx.x; e < NS * NS; e += blockDim.x) {
            int i = e / NS, j = e - i * NS;
            float c = -(cst[e] - lzs[i]) * weight[g[j]];
            if (isinf(c)) c = 1e8f;
            cst[e] = c;
        }
        __syncthreads();
        if (threadIdx.x >= 64) return;   // waves 1..3 done

        // ---- wave 0: shortest-augmenting-path Hungarian (f64 potentials) ----
        const int lane = threadIdx.x;
        const double INF = (double)INFINITY;
        double u_r = 0.0;   // lane r (1..20): row potential
        double v_j = 0.0;   // lane j (0..20): col potential
        int p_j = 0;        // lane j: row matched to col j (0 = free)
        int way_j = 0;
        const bool is_col = (lane >= 1 && lane <= NS);

        for (int i = 1; i <= NS; ++i) {
            if (lane == 0) p_j = i;      // p[0] = i
            int j0 = 0;
            double minv_j = INF;
            bool used_j = false;
            bool row_act = false;        // lane r: r ∈ p[used] so far
            while (true) {
                if (lane == j0) used_j = true;
                int i0 = __shfl(p_j, j0);
                if (lane == i0) row_act = true;       // p[used] grows by exactly i0
                double u_i0 = __shfl(u_r, i0);
                if (is_col && !used_j) {
                    double cur = (double)cst[(i0 - 1) * NS + (lane - 1)] - u_i0 - v_j;
                    if (cur < minv_j) { minv_j = cur; way_j = j0; }
                }
                double cand = (is_col && !used_j) ? minv_j : INF;
                int idx = lane;
                // width-32 butterfly argmin, low-index tie-break (np.argmin)
                for (int off = 1; off < 32; off <<= 1) {
                    double ov = __shfl_xor(cand, off, 32);
                    int    oi = __shfl_xor(idx, off, 32);
                    if (ov < cand || (ov == cand && oi < idx)) { cand = ov; idx = oi; }
                }
                double delta = __shfl(cand, 0);       // broadcast to all 64 lanes
                int    j1    = __shfl(idx, 0);
                if (row_act)     u_r += delta;        // u[p[used]] += delta
                if (used_j)      v_j -= delta;        // v[used]    -= delta
                else if (is_col) minv_j -= delta;     // minv[~used]-= delta
                j0 = j1;
                int pj0 = __shfl(p_j, j0);
                if (pj0 == 0) break;                  // free column reached
            }
            // augment along way[] chain
            while (j0 != 0) {
                int j1  = __shfl(way_j, j0);
                int pj1 = __shfl(p_j, j1);
                if (lane == j0) p_j = pj1;
                j0 = j1;
            }
        }
        // ans[p[j]-1] = j-1  ->  match[b][p[j]-1] = gold[b][j-1]
        if (is_col && p_j != 0) {
            match[b * NS + (p_j - 1)] = g[lane - 1];
        }
    } else {
        // =================== per-row logZ over C ===================
        const int row = blockIdx.x - NB;
        const float4* rp = (const float4*)(outputs + (size_t)row * NC);
        const int n4 = NC / 4;   // 8000

        float m = -INFINITY;
        float s = 0.f;
        for (int idx = threadIdx.x; idx < n4; idx += blockDim.x) {
            float4 x = rp[idx];
            float m4 = fmaxf(fmaxf(x.x, x.y), fmaxf(x.z, x.w));
            float nm = fmaxf(m, m4);
            s = s * __expf(m - nm)
              + __expf(x.x - nm) + __expf(x.y - nm)
              + __expf(x.z - nm) + __expf(x.w - nm);
            m = nm;
        }
        for (int off = 1; off < 64; off <<= 1) {
            float om = __shfl_xor(m, off);
            float os = __shfl_xor(s, off);
            float nm = fmaxf(m, om);
            s = s * __expf(m - nm) + os * __expf(om - nm);
            m = nm;
        }
        __shared__ float smx[4], ssm[4];
        int wid = threadIdx.x >> 6;
        if ((threadIdx.x & 63) == 0) { smx[wid] = m; ssm[wid] = s; }
        __syncthreads();
        if (threadIdx.x == 0) {
            float M = smx[0], S = ssm[0];
            for (int w = 1; w < 4; ++w) {
                float om = smx[w], os = ssm[w];
                float nm = fmaxf(M, om);
                S = S * __expf(M - nm) + os * __expf(om - nm);
                M = nm;
            }
            logZ[row] = M + __logf(S);
        }
    }
}

// ---------------------------------------------------------------------------
// Final masked-mean NLL reduce. Deterministic tree reduce, f64 accumulation.
// ---------------------------------------------------------------------------
__global__ __launch_bounds__(256) void final_kernel(
        const float* __restrict__ outputs,
        const int* __restrict__ match,
        const float* __restrict__ logZ,
        const float* __restrict__ weight,
        const unsigned char* __restrict__ mask,
        float* __restrict__ out) {
    double nsum = 0.0, msum = 0.0;
    for (int r = threadIdx.x; r < NB * NS; r += blockDim.x) {
        int mt = match[r];
        float x = outputs[(size_t)r * NC + mt];
        float nll = -(x - logZ[r]) * weight[mt];
        float mk = mask[r] ? 1.f : 0.f;
        nsum += (double)(nll * mk);
        msum += (double)mk;
    }
    for (int off = 1; off < 64; off <<= 1) {
        nsum += __shfl_xor(nsum, off);
        msum += __shfl_xor(msum, off);
    }
    __shared__ double sn[4], sm[4];
    int wid = threadIdx.x >> 6;
    if ((threadIdx.x & 63) == 0) { sn[wid] = nsum; sm[wid] = msum; }
    __syncthreads();
    if (threadIdx.x == 0) {
        double N = 0.0, M = 0.0;
        for (int w = 0; w < 4; ++w) { N += sn[w]; M += sm[w]; }
        out[0] = (float)(N / (M + 1e-8));
    }
}

// ---------------------------------------------------------------------------
extern "C" void kernel_launch(void* const* d_in, const int* in_sizes, int n_in,
                              void* d_out, int out_size, void* d_ws, size_t ws_size,
                              hipStream_t stream) {
    const float* outputs        = (const float*)d_in[0];          // [B,S,C] f32
    const int*   gold           = (const int*)d_in[1];            // [B,S] i32
    const unsigned char* mask   = (const unsigned char*)d_in[2];  // [B,S] bool
    const float* weight         = (const float*)d_in[3];          // [C] f32
    float* out = (float*)d_out;

    // workspace layout: match (B*S int) + logZ (B*S float)
    char* ws = (char*)d_ws;
    int*   match = (int*)ws;
    float* logZ  = (float*)(ws + (size_t)NB * NS * 4);

    mega_kernel<<<NB + NB * NS, 256, 0, stream>>>(outputs, gold, weight, match, logZ);
    final_kernel<<<1, 256, 0, stream>>>(outputs, match, logZ, weight, mask, out);
}